// Round 1
// baseline (332.172 us; speedup 1.0000x reference)
//
#include <hip/hip_runtime.h>
#include <math.h>

// Problem constants (fixed shapes)
#define DIM    4096
#define NH     32
#define NKV    8
#define HD     128
#define BS     16
#define KVLEN  4096
#define LASTPOS 4095
#define QKV_COLS 6144   // 4096 q + 1024 k + 1024 v

// ws layout (floats):
//   qkv     : [16][6144]          @ 0        (98304 floats)
//   attn_out: [16][4096]          @ 98304    (65536 floats)
//   partials: [128][8][4][130]    @ 163840   (532480 floats)
#define WS_QKV   0
#define WS_ATTN  98304
#define WS_PART  163840

// ---------------------------------------------------------------------------
// K1: qkv = x @ [wq|wk|wv], split-K with fp32 atomics.
// block: 256 threads, 2 cols/thread (512 cols/block); grid (12 colblocks, 32 kchunks)
// ---------------------------------------------------------------------------
__global__ __launch_bounds__(256) void qkv_proj(
    const float* __restrict__ x, const float* __restrict__ wq,
    const float* __restrict__ wk, const float* __restrict__ wv,
    float* __restrict__ qkv) {
  __shared__ float xs[16 * 128];
  const int tid = threadIdx.x;
  const int col = (blockIdx.x * 256 + tid) * 2;   // 0..6142, block-uniform matrix
  const int k0 = blockIdx.y * 128;

  for (int i = tid; i < 2048; i += 256) {
    int b = i >> 7, k = i & 127;
    xs[i] = x[b * DIM + k0 + k];
  }
  __syncthreads();

  const float* w;
  int wstride, wcol;
  if (col < 4096)      { w = wq; wstride = 4096; wcol = col; }
  else if (col < 5120) { w = wk; wstride = 1024; wcol = col - 4096; }
  else                 { w = wv; wstride = 1024; wcol = col - 5120; }
  const float* wp = w + (size_t)k0 * wstride + wcol;

  float acc0[16], acc1[16];
#pragma unroll
  for (int b = 0; b < 16; ++b) { acc0[b] = 0.f; acc1[b] = 0.f; }

  for (int k = 0; k < 128; k += 4) {
    float2 w0 = *(const float2*)(wp + (size_t)(k + 0) * wstride);
    float2 w1 = *(const float2*)(wp + (size_t)(k + 1) * wstride);
    float2 w2 = *(const float2*)(wp + (size_t)(k + 2) * wstride);
    float2 w3 = *(const float2*)(wp + (size_t)(k + 3) * wstride);
#pragma unroll
    for (int b = 0; b < 16; ++b) {
      float4 xb = *(const float4*)(&xs[b * 128 + k]);
      acc0[b] += xb.x * w0.x + xb.y * w1.x + xb.z * w2.x + xb.w * w3.x;
      acc1[b] += xb.x * w0.y + xb.y * w1.y + xb.z * w2.y + xb.w * w3.y;
    }
  }
#pragma unroll
  for (int b = 0; b < 16; ++b) {
    atomicAdd(&qkv[b * QKV_COLS + col],     acc0[b]);
    atomicAdd(&qkv[b * QKV_COLS + col + 1], acc1[b]);
  }
}

// ---------------------------------------------------------------------------
// K2: RoPE on q (scaled by 1/sqrt(HD)) and k, in place in qkv buffer.
// One thread per (b, head, pair). 16*40*64 = 40960 threads.
// ---------------------------------------------------------------------------
__global__ __launch_bounds__(256) void rope_kernel(
    float* __restrict__ qkv, const float* __restrict__ fc,
    const float* __restrict__ fs) {
  int t = blockIdx.x * 256 + threadIdx.x;
  if (t >= 16 * 40 * 64) return;
  int i  = t & 63;
  int hh = (t >> 6) % 40;
  int b  = t / (40 * 64);
  float c = fc[i], s = fs[i];
  int base;
  float scale;
  if (hh < 32) { base = b * QKV_COLS + hh * 128 + 2 * i; scale = 0.08838834764831845f; }
  else         { base = b * QKV_COLS + 4096 + (hh - 32) * 128 + 2 * i; scale = 1.0f; }
  float e = qkv[base], o = qkv[base + 1];
  qkv[base]     = (e * c - o * s) * scale;
  qkv[base + 1] = (e * s + o * c) * scale;
}

// ---------------------------------------------------------------------------
// K3: attention partials. block = (b, g, chunk of 512 kv positions).
// grid.x = 128 pairs * 8 chunks = 1024. 256 threads = 4 waves.
// Wave w: scores for t_local in [w*128, w*128+128); then head w softmax + PV.
// ---------------------------------------------------------------------------
__global__ __launch_bounds__(256) void attn_partial(
    const float* __restrict__ cache_k, const float* __restrict__ cache_v,
    const float* __restrict__ qkv, float* __restrict__ part) {
  __shared__ float qs[512];
  __shared__ float ss[4 * 512];
  const int tid = threadIdx.x;
  const int w = tid >> 6, lane = tid & 63;
  const int chunk = blockIdx.x & 7;
  const int bg = blockIdx.x >> 3;
  const int b = bg >> 3, g = bg & 7;

  qs[tid]       = qkv[b * QKV_COLS + g * 512 + tid];
  qs[tid + 256] = qkv[b * QKV_COLS + g * 512 + tid + 256];
  __syncthreads();

  float2 q0 = *(const float2*)(&qs[0 * 128 + 2 * lane]);
  float2 q1 = *(const float2*)(&qs[1 * 128 + 2 * lane]);
  float2 q2 = *(const float2*)(&qs[2 * 128 + 2 * lane]);
  float2 q3 = *(const float2*)(&qs[3 * 128 + 2 * lane]);

  const int t0 = chunk * 512;
  const float* kbase = cache_k + ((size_t)b * 4096 * 8 + g) * 128;
  const float* xk    = qkv + b * QKV_COLS + 4096 + g * 128;

  for (int j = 0; j < 128; ++j) {
    int tl = w * 128 + j;
    int t = t0 + tl;
    const float* krow = (t == LASTPOS) ? xk : (kbase + (size_t)t * 1024);
    float2 kv2 = ((const float2*)krow)[lane];
    float s0 = kv2.x * q0.x + kv2.y * q0.y;
    float s1 = kv2.x * q1.x + kv2.y * q1.y;
    float s2 = kv2.x * q2.x + kv2.y * q2.y;
    float s3 = kv2.x * q3.x + kv2.y * q3.y;
#pragma unroll
    for (int off = 1; off < 64; off <<= 1) {
      s0 += __shfl_xor(s0, off);
      s1 += __shfl_xor(s1, off);
      s2 += __shfl_xor(s2, off);
      s3 += __shfl_xor(s3, off);
    }
    if (lane < 4) {
      float v = (lane == 0) ? s0 : (lane == 1) ? s1 : (lane == 2) ? s2 : s3;
      ss[lane * 512 + tl] = v;
    }
  }
  __syncthreads();

  // softmax (chunk-local) for head w
  float vals[8];
  float m = -1e30f;
#pragma unroll
  for (int i = 0; i < 8; ++i) {
    vals[i] = ss[w * 512 + lane + 64 * i];
    m = fmaxf(m, vals[i]);
  }
#pragma unroll
  for (int off = 1; off < 64; off <<= 1) m = fmaxf(m, __shfl_xor(m, off));
  float l = 0.f;
#pragma unroll
  for (int i = 0; i < 8; ++i) {
    float p = __expf(vals[i] - m);
    ss[w * 512 + lane + 64 * i] = p;
    l += p;
  }
#pragma unroll
  for (int off = 1; off < 64; off <<= 1) l += __shfl_xor(l, off);

  float* prow = part + ((size_t)(bg * 8 + chunk) * 4 + w) * 130;
  if (lane == 0) { prow[128] = m; prow[129] = l; }
  __syncthreads();

  // PV: wave w = head w; lane covers d = 2*lane, 2*lane+1
  const float* vbase = cache_v + ((size_t)b * 4096 * 8 + g) * 128;
  const float* xv    = qkv + b * QKV_COLS + 5120 + g * 128;
  float accx = 0.f, accy = 0.f;
  const int nreg = (chunk == 7) ? 511 : 512;
  for (int tl = 0; tl < nreg; ++tl) {
    float2 vv = ((const float2*)(vbase + (size_t)(t0 + tl) * 1024))[lane];
    float p = ss[w * 512 + tl];
    accx += p * vv.x;
    accy += p * vv.y;
  }
  if (chunk == 7) {
    float2 vv = ((const float2*)xv)[lane];
    float p = ss[w * 512 + 511];
    accx += p * vv.x;
    accy += p * vv.y;
  }
  prow[2 * lane]     = accx;
  prow[2 * lane + 1] = accy;
}

// ---------------------------------------------------------------------------
// K4: combine 8 chunk-partials per (b,g,r,d) -> attn_out[b][h][d]
// ---------------------------------------------------------------------------
__global__ __launch_bounds__(256) void attn_combine(
    const float* __restrict__ part, float* __restrict__ attn_out) {
  int t = blockIdx.x * 256 + threadIdx.x;  // 65536
  int d = t & 127, r = (t >> 7) & 3, bg = t >> 9;
  int b = bg >> 3, g = bg & 7;
  float ms[8];
  float M = -1e30f;
#pragma unroll
  for (int c = 0; c < 8; ++c) {
    ms[c] = part[((size_t)(bg * 8 + c) * 4 + r) * 130 + 128];
    M = fmaxf(M, ms[c]);
  }
  float num = 0.f, den = 0.f;
#pragma unroll
  for (int c = 0; c < 8; ++c) {
    const float* prow = part + ((size_t)(bg * 8 + c) * 4 + r) * 130;
    float wgt = __expf(ms[c] - M);
    num += wgt * prow[d];
    den += wgt * prow[129];
  }
  attn_out[b * DIM + (g * 4 + r) * 128 + d] = num / den;
}

// ---------------------------------------------------------------------------
// K5: out = attn_out @ wo, split-K with fp32 atomics into zeroed d_out.
// grid (8 colblocks, 32 kchunks)
// ---------------------------------------------------------------------------
__global__ __launch_bounds__(256) void out_proj(
    const float* __restrict__ attn, const float* __restrict__ wo,
    float* __restrict__ out) {
  __shared__ float xs[16 * 128];
  const int tid = threadIdx.x;
  const int col = (blockIdx.x * 256 + tid) * 2;  // 0..4094
  const int k0 = blockIdx.y * 128;

  for (int i = tid; i < 2048; i += 256) {
    int b = i >> 7, k = i & 127;
    xs[i] = attn[b * DIM + k0 + k];
  }
  __syncthreads();

  const float* wp = wo + (size_t)k0 * 4096 + col;
  float acc0[16], acc1[16];
#pragma unroll
  for (int b = 0; b < 16; ++b) { acc0[b] = 0.f; acc1[b] = 0.f; }

  for (int k = 0; k < 128; k += 4) {
    float2 w0 = *(const float2*)(wp + (size_t)(k + 0) * 4096);
    float2 w1 = *(const float2*)(wp + (size_t)(k + 1) * 4096);
    float2 w2 = *(const float2*)(wp + (size_t)(k + 2) * 4096);
    float2 w3 = *(const float2*)(wp + (size_t)(k + 3) * 4096);
#pragma unroll
    for (int b = 0; b < 16; ++b) {
      float4 xb = *(const float4*)(&xs[b * 128 + k]);
      acc0[b] += xb.x * w0.x + xb.y * w1.x + xb.z * w2.x + xb.w * w3.x;
      acc1[b] += xb.x * w0.y + xb.y * w1.y + xb.z * w2.y + xb.w * w3.y;
    }
  }
#pragma unroll
  for (int b = 0; b < 16; ++b) {
    atomicAdd(&out[b * DIM + col],     acc0[b]);
    atomicAdd(&out[b * DIM + col + 1], acc1[b]);
  }
}

// ---------------------------------------------------------------------------
extern "C" void kernel_launch(void* const* d_in, const int* in_sizes, int n_in,
                              void* d_out, int out_size, void* d_ws, size_t ws_size,
                              hipStream_t stream) {
  const float* x  = (const float*)d_in[0];
  const float* wq = (const float*)d_in[1];
  const float* wk = (const float*)d_in[2];
  const float* wv = (const float*)d_in[3];
  const float* wo = (const float*)d_in[4];
  const float* ck = (const float*)d_in[5];
  const float* cv = (const float*)d_in[6];
  const float* fc = (const float*)d_in[7];
  const float* fs = (const float*)d_in[8];

  float* ws_f  = (float*)d_ws;
  float* qkv   = ws_f + WS_QKV;
  float* attn  = ws_f + WS_ATTN;
  float* part  = ws_f + WS_PART;
  float* out   = (float*)d_out;

  hipMemsetAsync(qkv, 0, 98304 * sizeof(float), stream);
  hipMemsetAsync(out, 0, 65536 * sizeof(float), stream);

  qkv_proj<<<dim3(12, 32), 256, 0, stream>>>(x, wq, wk, wv, qkv);
  rope_kernel<<<160, 256, 0, stream>>>(qkv, fc, fs);
  attn_partial<<<1024, 256, 0, stream>>>(ck, cv, qkv, part);
  attn_combine<<<256, 256, 0, stream>>>(part, attn);
  out_proj<<<dim3(8, 32), 256, 0, stream>>>(attn, wo, out);
}

// Round 2
// 202.338 us; speedup vs baseline: 1.6417x; 1.6417x over previous
//
#include <hip/hip_runtime.h>
#include <math.h>

// Problem constants (fixed shapes)
#define DIM    4096
#define NH     32
#define NKV    8
#define HD     128
#define BS     16
#define KVLEN  4096
#define LASTPOS 4095
#define QKV_COLS 6144   // 4096 q + 1024 k + 1024 v

// ws layout (floats):
//   qkv     : [16][6144]          @ 0        (98304 floats)
//   attn_out: [16][4096]          @ 98304    (65536 floats)
//   partials: [128][8][4][130]    @ 163840   (532480 floats)
#define WS_QKV   0
#define WS_ATTN  98304
#define WS_PART  163840

// ---------------------------------------------------------------------------
// K1: qkv = x @ [wq|wk|wv], split-K with fp32 atomics.
// block: 256 threads, 2 cols/thread (512 cols/block); grid (12 colblocks, 32 kchunks)
// ---------------------------------------------------------------------------
__global__ __launch_bounds__(256) void qkv_proj(
    const float* __restrict__ x, const float* __restrict__ wq,
    const float* __restrict__ wk, const float* __restrict__ wv,
    float* __restrict__ qkv) {
  __shared__ float xs[16 * 128];
  const int tid = threadIdx.x;
  const int col = (blockIdx.x * 256 + tid) * 2;   // 0..6142, block-uniform matrix
  const int k0 = blockIdx.y * 128;

  for (int i = tid; i < 2048; i += 256) {
    int b = i >> 7, k = i & 127;
    xs[i] = x[b * DIM + k0 + k];
  }
  __syncthreads();

  const float* w;
  int wstride, wcol;
  if (col < 4096)      { w = wq; wstride = 4096; wcol = col; }
  else if (col < 5120) { w = wk; wstride = 1024; wcol = col - 4096; }
  else                 { w = wv; wstride = 1024; wcol = col - 5120; }
  const float* wp = w + (size_t)k0 * wstride + wcol;

  float acc0[16], acc1[16];
#pragma unroll
  for (int b = 0; b < 16; ++b) { acc0[b] = 0.f; acc1[b] = 0.f; }

  for (int k = 0; k < 128; k += 4) {
    float2 w0 = *(const float2*)(wp + (size_t)(k + 0) * wstride);
    float2 w1 = *(const float2*)(wp + (size_t)(k + 1) * wstride);
    float2 w2 = *(const float2*)(wp + (size_t)(k + 2) * wstride);
    float2 w3 = *(const float2*)(wp + (size_t)(k + 3) * wstride);
#pragma unroll
    for (int b = 0; b < 16; ++b) {
      float4 xb = *(const float4*)(&xs[b * 128 + k]);
      acc0[b] += xb.x * w0.x + xb.y * w1.x + xb.z * w2.x + xb.w * w3.x;
      acc1[b] += xb.x * w0.y + xb.y * w1.y + xb.z * w2.y + xb.w * w3.y;
    }
  }
#pragma unroll
  for (int b = 0; b < 16; ++b) {
    atomicAdd(&qkv[b * QKV_COLS + col],     acc0[b]);
    atomicAdd(&qkv[b * QKV_COLS + col + 1], acc1[b]);
  }
}

// ---------------------------------------------------------------------------
// K2: RoPE on q (scaled by 1/sqrt(HD)) and k, in place in qkv buffer.
// ---------------------------------------------------------------------------
__global__ __launch_bounds__(256) void rope_kernel(
    float* __restrict__ qkv, const float* __restrict__ fc,
    const float* __restrict__ fs) {
  int t = blockIdx.x * 256 + threadIdx.x;
  if (t >= 16 * 40 * 64) return;
  int i  = t & 63;
  int hh = (t >> 6) % 40;
  int b  = t / (40 * 64);
  float c = fc[i], s = fs[i];
  int base;
  float scale;
  if (hh < 32) { base = b * QKV_COLS + hh * 128 + 2 * i; scale = 0.08838834764831845f; }
  else         { base = b * QKV_COLS + 4096 + (hh - 32) * 128 + 2 * i; scale = 1.0f; }
  float e = qkv[base], o = qkv[base + 1];
  qkv[base]     = (e * c - o * s) * scale;
  qkv[base + 1] = (e * s + o * c) * scale;
}

// ---------------------------------------------------------------------------
// K3: attention partials. block = (b, g, chunk of 512 kv positions).
// 512 threads = 8 waves.
// Scores: 16-lane groups own one K row each (4 rows/wave/iter), lane holds
//         8 d-elems, 4-deep shfl_xor reduce. Wave w covers rows [w*64,w*64+64).
// Softmax: waves 0-3, head = wave id (chunk-local, flash-style partial).
// PV: wave w covers rows [w*64, w*64+64) for ALL 4 heads (V read once/block),
//     cross-wave combine through LDS.
// ---------------------------------------------------------------------------
__global__ __launch_bounds__(512, 4) void attn_partial(
    const float* __restrict__ cache_k, const float* __restrict__ cache_v,
    const float* __restrict__ qkv, float* __restrict__ part) {
  __shared__ float qs[512];
  __shared__ float ss[4 * 512];
  __shared__ float pacc[8][4][128];
  const int tid = threadIdx.x;
  const int w = tid >> 6, lane = tid & 63;
  const int p = lane >> 4, ql = lane & 15;
  const int chunk = blockIdx.x & 7;
  const int bg = blockIdx.x >> 3;
  const int b = bg >> 3, g = bg & 7;

  qs[tid & 511] = qkv[b * QKV_COLS + g * 512 + (tid & 511)];
  __syncthreads();

  // Q fragments: head h, d-range [ql*8, ql*8+8)
  float4 qA[4], qB[4];
#pragma unroll
  for (int h = 0; h < 4; ++h) {
    qA[h] = *(const float4*)(&qs[h * 128 + ql * 8]);
    qB[h] = *(const float4*)(&qs[h * 128 + ql * 8 + 4]);
  }

  const int t0 = chunk * 512;
  const float* kbase = cache_k + ((size_t)b * 4096 * 8 + g) * 128;
  const float* xk    = qkv + b * QKV_COLS + 4096 + g * 128;

  // ---- scores ----
  for (int it = 0; it < 16; ++it) {
    int r = w * 64 + it * 4 + p;
    int t = t0 + r;
    const float* krow = (t == LASTPOS) ? xk : (kbase + (size_t)t * 1024);
    float4 k0 = *(const float4*)(krow + ql * 8);
    float4 k1 = *(const float4*)(krow + ql * 8 + 4);
    float s[4];
#pragma unroll
    for (int h = 0; h < 4; ++h) {
      s[h] = k0.x * qA[h].x + k0.y * qA[h].y + k0.z * qA[h].z + k0.w * qA[h].w
           + k1.x * qB[h].x + k1.y * qB[h].y + k1.z * qB[h].z + k1.w * qB[h].w;
    }
#pragma unroll
    for (int off = 1; off < 16; off <<= 1) {
#pragma unroll
      for (int h = 0; h < 4; ++h) s[h] += __shfl_xor(s[h], off);
    }
    float v = (ql == 0) ? s[0] : (ql == 1) ? s[1] : (ql == 2) ? s[2] : s[3];
    if (ql < 4) ss[ql * 512 + r] = v;
  }
  __syncthreads();

  // ---- chunk-local softmax, head = wave (waves 0-3) ----
  float* prow = part + ((size_t)(bg * 8 + chunk) * 4 + (w & 3)) * 130;
  if (w < 4) {
    float vals[8];
    float m = -1e30f;
#pragma unroll
    for (int i = 0; i < 8; ++i) {
      vals[i] = ss[w * 512 + lane + 64 * i];
      m = fmaxf(m, vals[i]);
    }
#pragma unroll
    for (int off = 1; off < 64; off <<= 1) m = fmaxf(m, __shfl_xor(m, off));
    float l = 0.f;
#pragma unroll
    for (int i = 0; i < 8; ++i) {
      float pe = __expf(vals[i] - m);
      ss[w * 512 + lane + 64 * i] = pe;
      l += pe;
    }
#pragma unroll
    for (int off = 1; off < 64; off <<= 1) l += __shfl_xor(l, off);
    if (lane == 0) { prow[128] = m; prow[129] = l; }
  }
  __syncthreads();

  // ---- PV: wave w covers rows [w*64, w*64+64) for all 4 heads ----
  const float* vbase = cache_v + ((size_t)b * 4096 * 8 + g) * 128;
  const float* xv    = qkv + b * QKV_COLS + 5120 + g * 128;
  float ax[4] = {0.f, 0.f, 0.f, 0.f}, ay[4] = {0.f, 0.f, 0.f, 0.f};
  for (int j = 0; j < 64; ++j) {
    int r = w * 64 + j;
    int t = t0 + r;
    const float* vrow = (t == LASTPOS) ? xv : (vbase + (size_t)t * 1024);
    float2 vv = ((const float2*)vrow)[lane];
    float p0 = ss[0 * 512 + r];
    float p1 = ss[1 * 512 + r];
    float p2 = ss[2 * 512 + r];
    float p3 = ss[3 * 512 + r];
    ax[0] += p0 * vv.x; ay[0] += p0 * vv.y;
    ax[1] += p1 * vv.x; ay[1] += p1 * vv.y;
    ax[2] += p2 * vv.x; ay[2] += p2 * vv.y;
    ax[3] += p3 * vv.x; ay[3] += p3 * vv.y;
  }
#pragma unroll
  for (int h = 0; h < 4; ++h) {
    pacc[w][h][2 * lane]     = ax[h];
    pacc[w][h][2 * lane + 1] = ay[h];
  }
  __syncthreads();

  // ---- cross-wave combine: 512 threads = 4 heads x 128 d ----
  {
    int h = tid >> 7, d = tid & 127;
    float sum = 0.f;
#pragma unroll
    for (int w2 = 0; w2 < 8; ++w2) sum += pacc[w2][h][d];
    part[((size_t)(bg * 8 + chunk) * 4 + h) * 130 + d] = sum;
  }
}

// ---------------------------------------------------------------------------
// K4: combine 8 chunk-partials per (b,g,r,d) -> attn_out[b][h][d]
// ---------------------------------------------------------------------------
__global__ __launch_bounds__(256) void attn_combine(
    const float* __restrict__ part, float* __restrict__ attn_out) {
  int t = blockIdx.x * 256 + threadIdx.x;  // 65536
  int d = t & 127, r = (t >> 7) & 3, bg = t >> 9;
  int b = bg >> 3, g = bg & 7;
  float ms[8];
  float M = -1e30f;
#pragma unroll
  for (int c = 0; c < 8; ++c) {
    ms[c] = part[((size_t)(bg * 8 + c) * 4 + r) * 130 + 128];
    M = fmaxf(M, ms[c]);
  }
  float num = 0.f, den = 0.f;
#pragma unroll
  for (int c = 0; c < 8; ++c) {
    const float* prow = part + ((size_t)(bg * 8 + c) * 4 + r) * 130;
    float wgt = __expf(ms[c] - M);
    num += wgt * prow[d];
    den += wgt * prow[129];
  }
  attn_out[b * DIM + (g * 4 + r) * 128 + d] = num / den;
}

// ---------------------------------------------------------------------------
// K5: out = attn_out @ wo, split-K with fp32 atomics into zeroed d_out.
// ---------------------------------------------------------------------------
__global__ __launch_bounds__(256) void out_proj(
    const float* __restrict__ attn, const float* __restrict__ wo,
    float* __restrict__ out) {
  __shared__ float xs[16 * 128];
  const int tid = threadIdx.x;
  const int col = (blockIdx.x * 256 + tid) * 2;  // 0..4094
  const int k0 = blockIdx.y * 128;

  for (int i = tid; i < 2048; i += 256) {
    int b = i >> 7, k = i & 127;
    xs[i] = attn[b * DIM + k0 + k];
  }
  __syncthreads();

  const float* wp = wo + (size_t)k0 * 4096 + col;
  float acc0[16], acc1[16];
#pragma unroll
  for (int b = 0; b < 16; ++b) { acc0[b] = 0.f; acc1[b] = 0.f; }

  for (int k = 0; k < 128; k += 4) {
    float2 w0 = *(const float2*)(wp + (size_t)(k + 0) * 4096);
    float2 w1 = *(const float2*)(wp + (size_t)(k + 1) * 4096);
    float2 w2 = *(const float2*)(wp + (size_t)(k + 2) * 4096);
    float2 w3 = *(const float2*)(wp + (size_t)(k + 3) * 4096);
#pragma unroll
    for (int b = 0; b < 16; ++b) {
      float4 xb = *(const float4*)(&xs[b * 128 + k]);
      acc0[b] += xb.x * w0.x + xb.y * w1.x + xb.z * w2.x + xb.w * w3.x;
      acc1[b] += xb.x * w0.y + xb.y * w1.y + xb.z * w2.y + xb.w * w3.y;
    }
  }
#pragma unroll
  for (int b = 0; b < 16; ++b) {
    atomicAdd(&out[b * DIM + col],     acc0[b]);
    atomicAdd(&out[b * DIM + col + 1], acc1[b]);
  }
}

// ---------------------------------------------------------------------------
extern "C" void kernel_launch(void* const* d_in, const int* in_sizes, int n_in,
                              void* d_out, int out_size, void* d_ws, size_t ws_size,
                              hipStream_t stream) {
  const float* x  = (const float*)d_in[0];
  const float* wq = (const float*)d_in[1];
  const float* wk = (const float*)d_in[2];
  const float* wv = (const float*)d_in[3];
  const float* wo = (const float*)d_in[4];
  const float* ck = (const float*)d_in[5];
  const float* cv = (const float*)d_in[6];
  const float* fc = (const float*)d_in[7];
  const float* fs = (const float*)d_in[8];

  float* ws_f  = (float*)d_ws;
  float* qkv   = ws_f + WS_QKV;
  float* attn  = ws_f + WS_ATTN;
  float* part  = ws_f + WS_PART;
  float* out   = (float*)d_out;

  hipMemsetAsync(qkv, 0, 98304 * sizeof(float), stream);
  hipMemsetAsync(out, 0, 65536 * sizeof(float), stream);

  qkv_proj<<<dim3(12, 32), 256, 0, stream>>>(x, wq, wk, wv, qkv);
  rope_kernel<<<160, 256, 0, stream>>>(qkv, fc, fs);
  attn_partial<<<1024, 512, 0, stream>>>(ck, cv, qkv, part);
  attn_combine<<<256, 256, 0, stream>>>(part, attn);
  out_proj<<<dim3(8, 32), 256, 0, stream>>>(attn, wo, out);
}